// Round 14
// baseline (615.621 us; speedup 1.0000x reference)
//
#include <hip/hip_runtime.h>
#include <math.h>

#define R_ 512
#define C_ 512
#define E_ 256
#define H_ 8
#define D_ 32
#define RC_ (R_*C_)   // 262144
#define RP 136        // repack pitch (ushorts)

typedef __attribute__((ext_vector_type(8))) short bf16x8;
typedef __attribute__((ext_vector_type(4))) float f32x4;

__device__ __forceinline__ ushort f2bf(float f) {
    union { float f; unsigned u; } v; v.f = f;
    unsigned r = v.u + 0x7FFFu + ((v.u >> 16) & 1u);   // RNE
    return (ushort)(r >> 16);
}
__device__ __forceinline__ float bf2f(ushort u) {
    union { unsigned u; float f; } v; v.u = ((unsigned)u) << 16;
    return v.f;
}
// packed f32x2 -> bf16x2 (T12 primitive; RNE on gfx950)
__device__ __forceinline__ unsigned cvtpk(float lo, float hi) {
    unsigned r;
    asm("v_cvt_pk_bf16_f32 %0, %1, %2" : "=v"(r) : "v"(lo), "v"(hi));
    return r;
}

// 16B global->LDS direct copy (lane-linear dest), fallback = reg staging.
__device__ __forceinline__ void gll16(const ushort* g, ushort* l) {
#if __has_builtin(__builtin_amdgcn_global_load_lds)
    __builtin_amdgcn_global_load_lds(
        (const __attribute__((address_space(1))) unsigned*)(unsigned long long)g,
        (__attribute__((address_space(3))) unsigned*)(unsigned)(unsigned long long)l,
        16, 0, 0);
#else
    *(uint4*)l = *(const uint4*)g;
#endif
}

// Stage one 16B chunk f of a [rows][32-ushort] bf16 tile.  Source slot
// XOR-swizzled with (row>>1)&3 (verified r7).  LDS dest lane-linear.
#define SCH(gbase, stride, lds, f)                                               \
    gll16((gbase) + (size_t)((f) >> 2) * (stride)                                \
              + (((((f) & 3) ^ ((((f) >> 2) >> 1) & 3))) << 3),                  \
          (lds) + (f) * 8)

// --- Fenced sync primitives (validated r11/r12: rule #18 double-fence).
#define SCHED0   __builtin_amdgcn_sched_barrier(0)
#define ABAR     __builtin_amdgcn_s_barrier()
#define VMCNT(N) asm volatile("s_waitcnt vmcnt(" #N ")" ::: "memory")
#define LGKM0    asm volatile("s_waitcnt lgkmcnt(0)" ::: "memory")
#define SYNC_IN(N) do { VMCNT(N); SCHED0; ABAR; SCHED0; } while (0)
#define SYNC_OUT   do { LGKM0; SCHED0; ABAR; SCHED0; } while (0)

// Per-wave 64x64 output, 16x16x32 bf16 MFMA, K=32 per step, 32-ushort rows.
#define PREAMBLE(WM, WN)                                \
    const int t = threadIdx.x;                          \
    const int wid = t >> 6, l = t & 63;                 \
    const int wm = (WM), wn = (WN);                     \
    const int l15 = l & 15, lhi = l >> 4;               \
    const int swz8 = (lhi ^ ((l15 >> 1) & 3)) * 8;      \
    f32x4 acc[4][4];                                    \
    _Pragma("unroll")                                   \
    for (int a_ = 0; a_ < 4; ++a_)                      \
        _Pragma("unroll")                               \
        for (int b_ = 0; b_ < 4; ++b_)                  \
            acc[a_][b_] = (f32x4){0.f, 0.f, 0.f, 0.f};

#define MFMA_STEP(As, Bs)                                                        \
    {                                                                            \
        bf16x8 af_[4], bf_[4];                                                   \
        _Pragma("unroll")                                                        \
        for (int f_ = 0; f_ < 4; ++f_) {                                         \
            af_[f_] = *(const bf16x8*)((As) + (wm*64 + f_*16 + l15)*32 + swz8);  \
            bf_[f_] = *(const bf16x8*)((Bs) + (wn*64 + f_*16 + l15)*32 + swz8);  \
        }                                                                        \
        _Pragma("unroll")                                                        \
        for (int m_ = 0; m_ < 4; ++m_)                                           \
            _Pragma("unroll")                                                    \
            for (int n_ = 0; n_ < 4; ++n_)                                       \
                acc[m_][n_] = __builtin_amdgcn_mfma_f32_16x16x32_bf16(           \
                    af_[m_], bf_[n_], acc[m_][n_], 0, 0, 0);                     \
    }

// Triple-buffered K-loop, ONE fenced barrier per step, prefetch distance 2
// (validated r12).  Requires A0..A2/B0..B2; each STG = 4 gll16/thread.
#define DBUFT(STG, NIT)                                                          \
    STG(0, A0, B0); STG(1, A1, B1);                                              \
    _Pragma("unroll")                                                            \
    for (int s = 0; s < (NIT); ++s) {                                            \
        if (s < (NIT) - 1) { VMCNT(4); } else { VMCNT(0); }                      \
        SCHED0; ABAR; SCHED0;                                                    \
        if (s + 2 < (NIT)) {                                                     \
            if (((s + 2) % 3) == 0)      { STG(s + 2, A0, B0); }                 \
            else if (((s + 2) % 3) == 1) { STG(s + 2, A1, B1); }                 \
            else                         { STG(s + 2, A2, B2); }                 \
        }                                                                        \
        if ((s % 3) == 0)      { MFMA_STEP(A0, B0); }                            \
        else if ((s % 3) == 1) { MFMA_STEP(A1, B1); }                            \
        else                   { MFMA_STEP(A2, B2); }                            \
    }

#define BUFS3 ushort* A0 = S;          ushort* B0 = S + 4096;                    \
              ushort* A1 = S + 8192;   ushort* B1 = S + 12288;                   \
              ushort* A2 = S + 16384;  ushort* B2 = S + 20480;

// ---------------------------------------------------------------------------
// Weights -> n-major bf16.
// ---------------------------------------------------------------------------
__global__ __launch_bounds__(256) void convert_w(
    const float* __restrict__ Wq, const float* __restrict__ Wk,
    const float* __restrict__ Wv, const float* __restrict__ Wo,
    ushort* __restrict__ WTqkv, ushort* __restrict__ WoT)
{
    const int id = blockIdx.x;      // 0..1023
    const int matn = id >> 8;
    const int n = id & 255;
    const int k = threadIdx.x;
    const float* W = (matn == 0) ? Wq : (matn == 1) ? Wk : (matn == 2) ? Wv : Wo;
    ushort v = f2bf(W[(size_t)k * E_ + n]);
    if (matn < 3) WTqkv[((size_t)matn * E_ + n) * E_ + k] = v;
    else          WoT[(size_t)n * E_ + k] = v;
}

// ---------------------------------------------------------------------------
// Fused QKV projection, conversion fused (no separate convert_x pass).
// A staged as fp32 via gll16 ([128][32 f32]), 3-bit chunk key (row&7):
// stored slot = src_chunk ^ (row&7) -> each 4-bank group serves exactly
// 8 lanes on the fragment read (conflict floor).  Read reconstructs source
// k-order via two b128s at slots (2*lhi)^(l15&7), (2*lhi+1)^(l15&7); cvt to
// bf16 with v_cvt_pk_bf16_f32.  B staged bf16 as before.  Fenced 2-buffer
// DBUFC, VMCNT(6) counted.  12288 blocks x 256 thr (4 waves 2x2).
// ---------------------------------------------------------------------------
__global__ __launch_bounds__(256) void qkv_mfma(
    const float* __restrict__ x, const ushort* __restrict__ WT,
    const float* __restrict__ bq, const float* __restrict__ bk,
    const float* __restrict__ bv, const float* __restrict__ mask,
    ushort* __restrict__ qb, ushort* __restrict__ kb, ushort* __restrict__ vb)
{
    __shared__ __align__(16) ushort S[24576];   // 48KB; repack aliases front
    float*  Af0 = (float*)S;            // 16KB  [128][32] f32
    float*  Af1 = (float*)(S + 8192);   // 16KB
    ushort* B0  = S + 16384;            // 8KB   [128][32] bf16
    ushort* B1  = S + 20480;            // 8KB
    const int id = ((blockIdx.x & 7) * 1536) + (blockIdx.x >> 3);
    const int nt = id % 6;
    const int rc0 = (id / 6) * 128;
    const int t = threadIdx.x;
    const int wid = t >> 6, l = t & 63;
    const int wm = wid >> 1, wn = wid & 1;
    const int l15 = l & 15, lhi = l >> 4;
    const int swz8 = (lhi ^ ((l15 >> 1) & 3)) * 8;   // B read (bf16 rows)
    const int pA1 = (((2 * lhi)     ^ (l15 & 7)) * 4);  // A read slot 1 (f32)
    const int pA2 = (((2 * lhi + 1) ^ (l15 & 7)) * 4);  // A read slot 2 (f32)
    f32x4 acc[4][4];
    #pragma unroll
    for (int a_ = 0; a_ < 4; ++a_)
        #pragma unroll
        for (int b_ = 0; b_ < 4; ++b_)
            acc[a_][b_] = (f32x4){0.f, 0.f, 0.f, 0.f};

    const float*  Ab = x + (size_t)rc0 * E_;
    const ushort* Bb = WT + (size_t)nt * 128 * E_;

// A: 1024 16B-chunks (4/thread); row=f>>3, stored slot (f&7), source chunk
// (f&7)^(row&7) [involution].  B: 512 chunks (2/thread), standard SCH.
#define QSTG(i, Af, Bbuf) {                                                      \
    _Pragma("unroll")                                                            \
    for (int c2 = 0; c2 < 4; ++c2) {                                             \
        const int f = t + 256 * c2;                                              \
        const int row = f >> 3;                                                  \
        const int cc = (f & 7) ^ (row & 7);                                      \
        gll16((const ushort*)(Ab + (size_t)row * E_ + (i) * 32 + cc * 4),        \
              (ushort*)((Af) + f * 4));                                          \
    }                                                                            \
    const ushort* Bi = Bb + (i) * 32;                                            \
    SCH(Bi, E_, Bbuf, t); SCH(Bi, E_, Bbuf, t + 256); }

// Fragment read: A fp32 (two swizzled b128s, source-k order) -> cvt_pk ->
// bf16x8; B as usual; 16 MFMA.
#define QMFMA(Af, Bs) {                                                          \
    bf16x8 af_[4], bf_[4];                                                       \
    _Pragma("unroll")                                                            \
    for (int f_ = 0; f_ < 4; ++f_) {                                             \
        const float* ap_ = (Af) + (wm*64 + f_*16 + l15) * 32;                    \
        float4 xa_ = *(const float4*)(ap_ + pA1);                                \
        float4 xc_ = *(const float4*)(ap_ + pA2);                                \
        union { unsigned u[4]; bf16x8 v; } pk_;                                  \
        pk_.u[0] = cvtpk(xa_.x, xa_.y); pk_.u[1] = cvtpk(xa_.z, xa_.w);          \
        pk_.u[2] = cvtpk(xc_.x, xc_.y); pk_.u[3] = cvtpk(xc_.z, xc_.w);          \
        af_[f_] = pk_.v;                                                         \
        bf_[f_] = *(const bf16x8*)((Bs) + (wn*64 + f_*16 + l15)*32 + swz8);      \
    }                                                                            \
    _Pragma("unroll")                                                            \
    for (int m_ = 0; m_ < 4; ++m_)                                               \
        _Pragma("unroll")                                                        \
        for (int n_ = 0; n_ < 4; ++n_)                                           \
            acc[m_][n_] = __builtin_amdgcn_mfma_f32_16x16x32_bf16(               \
                af_[m_], bf_[n_], acc[m_][n_], 0, 0, 0); }

    // 8 K-steps, 2-buffer fenced DBUFC (r11 pattern), counted VMCNT(6).
    QSTG(0, Af0, B0);
    #pragma unroll
    for (int itp = 0; itp < 4; ++itp) {
        QSTG(2*itp + 1, Af1, B1);
        SYNC_IN(6);
        QMFMA(Af0, B0);
        SYNC_OUT;
        if (itp < 3) { QSTG(2*itp + 2, Af0, B0); SYNC_IN(6); }
        else         { SYNC_IN(0); }
        QMFMA(Af1, B1);
        SYNC_OUT;
    }

    const int proj = nt >> 1;
    const float* bias = (proj == 0) ? bq : (proj == 1) ? bk : bv;
    float bvv[4];
    #pragma unroll
    for (int fn = 0; fn < 4; ++fn)
        bvv[fn] = bias[(nt * 128 + wn * 64 + fn * 16 + l15) & 255];

    // repack: q/k as [c][e], v as [e][c]
    #pragma unroll
    for (int fm = 0; fm < 4; ++fm)
        #pragma unroll
        for (int fn = 0; fn < 4; ++fn)
            #pragma unroll
            for (int rg = 0; rg < 4; ++rg) {
                const int m = wm * 64 + fm * 16 + lhi * 4 + rg;
                const int n = wn * 64 + fn * 16 + l15;
                const ushort val = f2bf(acc[fm][fn][rg] + bvv[fn]);
                if (proj < 2) S[m * RP + n] = val;
                else          S[n * RP + m] = val;
            }
    __syncthreads();

    const int r = rc0 >> 9, c0 = rc0 & 511;
    if (proj < 2) {
        ushort* dst = (proj == 0) ? qb : kb;
        #pragma unroll
        for (int c = 0; c < 8; ++c) {
            const int idx = t + 256 * c;
            const int mrow = idx >> 4, ne = (idx & 15) * 8;
            uint4 w = *(const uint4*)(S + mrow * RP + ne);
            if (proj == 0) {   // q: * 1/128 * (1-mask)
                const float sk = 0.0078125f * (1.0f - mask[rc0 + mrow]);
                ushort* ws = (ushort*)&w;
                #pragma unroll
                for (int jj = 0; jj < 8; ++jj) ws[jj] = f2bf(bf2f(ws[jj]) * sk);
            }
            const int e = (nt & 1) * 128 + ne, h = e >> 5, d = e & 31;
            *(uint4*)(dst + ((((size_t)h * R_ + r) * C_) + c0 + mrow) * D_ + d) = w;
        }
    } else {
        #pragma unroll
        for (int c = 0; c < 8; ++c) {
            const int idx = t + 256 * c;
            const int nrow = idx >> 4, m0 = (idx & 15) * 8;
            uint4 w = *(const uint4*)(S + nrow * RP + m0);
            const int e = (nt & 1) * 128 + nrow, h = e >> 5, d = e & 31;
            *(uint4*)(vb + (((size_t)h * R_ + r) * D_ + d) * C_ + c0 + m0) = w;
        }
    }
#undef QSTG
#undef QMFMA
}

// ---------------------------------------------------------------------------
// Attention logits.  128x128 tile, 256 threads, K split 8-way (1024 blocks).
// ---------------------------------------------------------------------------
__global__ __launch_bounds__(256) void logits_mfma(
    const ushort* __restrict__ qb, const ushort* __restrict__ kb,
    float* __restrict__ partial)
{
    __shared__ __align__(16) ushort S[24576];
    BUFS3;
    const int id = ((blockIdx.x & 7) * 128) + (blockIdx.x >> 3);
    const int sub = id & 15;
    const int j0 = (sub & 3) * 128;         // j fastest: 4 blocks share q panel
    const int i0 = (sub >> 2) * 128;
    const int hks = id >> 4;                // 0..63
    const int h = hks >> 3, ks = hks & 7;
    PREAMBLE(wid >> 1, wid & 1);

    const ushort* Ab = qb + (((size_t)h * R_ + ks * 64) * C_ + i0) * D_;
    const ushort* Bb = kb + (((size_t)h * R_ + ks * 64) * C_ + j0) * D_;

#define LSTG(i, Abuf, Bbuf) {                                   \
    const ushort* Ai = Ab + (size_t)(i) * (C_ * D_);            \
    const ushort* Bi = Bb + (size_t)(i) * (C_ * D_);            \
    SCH(Ai, D_, Abuf, t); SCH(Ai, D_, Abuf, t + 256);           \
    SCH(Bi, D_, Bbuf, t); SCH(Bi, D_, Bbuf, t + 256); }
    DBUFT(LSTG, 64);

    float* dst = partial + ((size_t)ks * H_ + h) * C_ * C_;
    #pragma unroll
    for (int fm = 0; fm < 4; ++fm)
        #pragma unroll
        for (int rg = 0; rg < 4; ++rg) {
            const int i = i0 + wm * 64 + fm * 16 + lhi * 4 + rg;
            #pragma unroll
            for (int fn = 0; fn < 4; ++fn) {
                const int j = j0 + wn * 64 + fn * 16 + l15;
                dst[(size_t)i * C_ + j] = acc[fm][fn][rg];
            }
        }
}

// ---------------------------------------------------------------------------
// Sum 8 K-split partials + i-axis mask + softmax over j.
// ---------------------------------------------------------------------------
__global__ __launch_bounds__(256) void softmax_kernel(
    const float* __restrict__ partial, const float* __restrict__ mask,
    float* __restrict__ probs, ushort* __restrict__ Pb)
{
    const int hi = blockIdx.x;
    const int i = hi & 511;
    const int t = threadIdx.x;
    const size_t base = (size_t)hi * C_;
    const size_t stride = (size_t)H_ * C_ * C_;
    float v0 = 0.f, v1 = 0.f;
    #pragma unroll
    for (int ksp = 0; ksp < 8; ++ksp) {
        v0 += partial[ksp * stride + base + t];
        v1 += partial[ksp * stride + base + t + 256];
    }
    const float mi = mask[i];
    const float keep = 1.0f - mi;
    v0 = v0 * keep + mi * (-10000.0f);
    v1 = v1 * keep + mi * (-10000.0f);

    float m = fmaxf(v0, v1);
    #pragma unroll
    for (int off = 32; off > 0; off >>= 1) m = fmaxf(m, __shfl_xor(m, off));
    __shared__ float red[4];
    if ((t & 63) == 0) red[t >> 6] = m;
    __syncthreads();
    m = fmaxf(fmaxf(red[0], red[1]), fmaxf(red[2], red[3]));

    const float e0 = expf(v0 - m), e1 = expf(v1 - m);
    float s = e0 + e1;
    #pragma unroll
    for (int off = 32; off > 0; off >>= 1) s += __shfl_xor(s, off);
    __syncthreads();
    if ((t & 63) == 0) red[t >> 6] = s;
    __syncthreads();
    s = red[0] + red[1] + red[2] + red[3];

    const float inv = 1.0f / s;
    const float p0 = e0 * inv, p1 = e1 * inv;
    probs[base + t] = p0;
    probs[base + t + 256] = p1;
    Pb[base + t] = f2bf(p0);
    Pb[base + t + 256] = f2bf(p1);
}

// ---------------------------------------------------------------------------
// Context.  128x128 tile, 256 threads, 4096 blocks (one head per XCD).
// ---------------------------------------------------------------------------
__global__ __launch_bounds__(256) void context_mfma(
    const ushort* __restrict__ Pb, const ushort* __restrict__ vb,
    ushort* __restrict__ ctxb)
{
    __shared__ __align__(16) ushort S[24576];
    BUFS3;
    const int id = ((blockIdx.x & 7) * 512) + (blockIdx.x >> 3);
    const int i0 = (id & 3) * 128;          // i fastest: 4 blocks share vb panel
    const int n0 = ((id >> 2) & 127) * 128;
    const int h = id >> 9;
    PREAMBLE(wid >> 1, wid & 1);

    const ushort* Ab = Pb + ((size_t)h * C_ + i0) * C_;
    const ushort* Bb = vb + ((size_t)h * R_ * D_ + n0) * C_;

#define CSTG(i, Abuf, Bbuf) {                                   \
    const ushort* Ai = Ab + (i) * 32;                           \
    const ushort* Bi = Bb + (i) * 32;                           \
    SCH(Ai, C_, Abuf, t); SCH(Ai, C_, Abuf, t + 256);           \
    SCH(Bi, C_, Bbuf, t); SCH(Bi, C_, Bbuf, t + 256); }
    DBUFT(CSTG, 16);
    __syncthreads();   // staging reads done before repack alias

    #pragma unroll
    for (int fm = 0; fm < 4; ++fm)
        #pragma unroll
        for (int fn = 0; fn < 4; ++fn)
            #pragma unroll
            for (int rg = 0; rg < 4; ++rg) {
                const int m = wm * 64 + fm * 16 + lhi * 4 + rg;
                const int n = wn * 64 + fn * 16 + l15;
                S[m * RP + n] = f2bf(acc[fm][fn][rg]);
            }
    __syncthreads();

    #pragma unroll
    for (int c = 0; c < 8; ++c) {
        const int idx = t + 256 * c;
        const int mrow = idx >> 4, nl = (idx & 15) * 8;
        uint4 w = *(const uint4*)(S + mrow * RP + nl);
        const int n = n0 + nl;
        const int rr = n >> 5, d = n & 31;
        const size_t rc = (size_t)rr * C_ + i0 + mrow;
        *(uint4*)(ctxb + rc * E_ + h * D_ + d) = w;
    }
}

// ---------------------------------------------------------------------------
// Output projection.  128x128 tile, 256 threads, 4096 blocks, fp32 out.
// ---------------------------------------------------------------------------
__global__ __launch_bounds__(256) void out_proj_mfma(
    const ushort* __restrict__ ctxb, const ushort* __restrict__ WoT,
    const float* __restrict__ bo, float* __restrict__ out)
{
    __shared__ __align__(16) ushort S[24576];
    BUFS3;
    float* Sf = (float*)S;                  // 128 x 68 fp32 repack (aliases)
    const int id = ((blockIdx.x & 7) * 512) + (blockIdx.x >> 3);
    const int n0 = (id & 1) * 128;
    const int rc0 = (id >> 1) * 128;
    PREAMBLE(wid >> 1, wid & 1);

    const ushort* Ab = ctxb + (size_t)rc0 * E_;
    const ushort* Bb = WoT + (size_t)n0 * E_;

#define OSTG(i, Abuf, Bbuf) {                                   \
    const ushort* Ai = Ab + (i) * 32;                           \
    const ushort* Bi = Bb + (i) * 32;                           \
    SCH(Ai, E_, Abuf, t); SCH(Ai, E_, Abuf, t + 256);           \
    SCH(Bi, E_, Bbuf, t); SCH(Bi, E_, Bbuf, t + 256); }
    DBUFT(OSTG, 8);
    __syncthreads();   // staging reads done before repack alias

    float bvv[4];
    #pragma unroll
    for (int fn = 0; fn < 4; ++fn)
        bvv[fn] = bo[n0 + wn * 64 + fn * 16 + l15];

    #pragma unroll
    for (int p = 0; p < 2; ++p) {
        #pragma unroll
        for (int fm = 0; fm < 4; ++fm)
            #pragma unroll
            for (int fh = 0; fh < 2; ++fh) {
                const int fn = 2 * p + fh;
                #pragma unroll
                for (int rg = 0; rg < 4; ++rg) {
                    const int m = wm * 64 + fm * 16 + lhi * 4 + rg;
                    const int s = wn * 32 + fh * 16 + l15;
                    Sf[m * 68 + s] = acc[fm][fn][rg] + bvv[fn];
                }
            }
        __syncthreads();
        #pragma unroll
        for (int c = 0; c < 8; ++c) {
            const int idx = t + 256 * c;
            const int row = idx >> 4, s0 = (idx & 15) * 4;
            float4 w = *(const float4*)(Sf + row * 68 + s0);
            const int ncol = n0 + (s0 >> 5) * 64 + (2 * p + ((s0 >> 4) & 1)) * 16 + (s0 & 15);
            *(float4*)(out + ((size_t)rc0 + row) * E_ + ncol) = w;
        }
        __syncthreads();
    }
}

// ---------------------------------------------------------------------------
extern "C" void kernel_launch(void* const* d_in, const int* in_sizes, int n_in,
                              void* d_out, int out_size, void* d_ws, size_t ws_size,
                              hipStream_t stream)
{
    const float* x    = (const float*)d_in[0];
    const float* mask = (const float*)d_in[1];
    const float* Wq   = (const float*)d_in[2];
    const float* bq   = (const float*)d_in[3];
    const float* Wk   = (const float*)d_in[4];
    const float* bk   = (const float*)d_in[5];
    const float* Wv   = (const float*)d_in[6];
    const float* bv   = (const float*)d_in[7];
    const float* Wo   = (const float*)d_in[8];
    const float* bo   = (const float*)d_in[9];

    float* out   = (float*)d_out;                       // [R,C,E] fp32
    float* probs = out + (size_t)RC_ * E_;              // [H,C,C] fp32

    char* ws = (char*)d_ws;
    ushort* qb      = (ushort*)(ws);                    // 128 MB  [h][r][c][d]
    ushort* kb      = (ushort*)(ws + 134217728ull);     // 128 MB  [h][r][c][d]
    ushort* vb      = (ushort*)(ws + 268435456ull);     // 128 MB  [h][r][d][c]
    ushort* ctxb    = (ushort*)(ws + 402653184ull);     // 128 MB  [rc][e]
    float*  partial = (float*)(ws + 536870912ull);      // 64 MB   [8][h][i][j]
    ushort* Pb      = (ushort*)(ws + 603979776ull);     // 4 MB    [h][i][j]
    ushort* WTqkv   = (ushort*)(ws + 608174080ull);     // 384 KB
    ushort* WoT     = (ushort*)(ws + 608567296ull);     // 128 KB

    convert_w<<<1024, 256, 0, stream>>>(Wq, Wk, Wv, Wo, WTqkv, WoT);
    qkv_mfma<<<12288, 256, 0, stream>>>(x, WTqkv, bq, bk, bv, mask, qb, kb, vb);
    logits_mfma<<<1024, 256, 0, stream>>>(qb, kb, partial);
    softmax_kernel<<<4096, 256, 0, stream>>>(partial, mask, probs, Pb);
    context_mfma<<<4096, 256, 0, stream>>>(Pb, vb, ctxb);
    out_proj_mfma<<<4096, 256, 0, stream>>>(ctxb, WoT, bo, out);
}

// Round 15
// 603.490 us; speedup vs baseline: 1.0201x; 1.0201x over previous
//
#include <hip/hip_runtime.h>
#include <math.h>

#define R_ 512
#define C_ 512
#define E_ 256
#define H_ 8
#define D_ 32
#define RC_ (R_*C_)   // 262144
#define RP 136        // repack pitch (ushorts)

typedef __attribute__((ext_vector_type(8))) short bf16x8;
typedef __attribute__((ext_vector_type(4))) float f32x4;

__device__ __forceinline__ ushort f2bf(float f) {
    union { float f; unsigned u; } v; v.f = f;
    unsigned r = v.u + 0x7FFFu + ((v.u >> 16) & 1u);   // RNE
    return (ushort)(r >> 16);
}
__device__ __forceinline__ float bf2f(ushort u) {
    union { unsigned u; float f; } v; v.u = ((unsigned)u) << 16;
    return v.f;
}
// packed f32x2 -> bf16x2 (RNE on gfx950)
__device__ __forceinline__ unsigned cvtpk(float lo, float hi) {
    unsigned r;
    asm("v_cvt_pk_bf16_f32 %0, %1, %2" : "=v"(r) : "v"(lo), "v"(hi));
    return r;
}

// 16B global->LDS direct copy (lane-linear dest), fallback = reg staging.
__device__ __forceinline__ void gll16(const ushort* g, ushort* l) {
#if __has_builtin(__builtin_amdgcn_global_load_lds)
    __builtin_amdgcn_global_load_lds(
        (const __attribute__((address_space(1))) unsigned*)(unsigned long long)g,
        (__attribute__((address_space(3))) unsigned*)(unsigned)(unsigned long long)l,
        16, 0, 0);
#else
    *(uint4*)l = *(const uint4*)g;
#endif
}

// Stage one 16B chunk f of a [rows][32-ushort] bf16 tile.  Source slot
// XOR-swizzled with (row>>1)&3 (r12-proven key).  LDS dest lane-linear.
#define SCH(gbase, stride, lds, f)                                               \
    gll16((gbase) + (size_t)((f) >> 2) * (stride)                                \
              + (((((f) & 3) ^ ((((f) >> 2) >> 1) & 3))) << 3),                  \
          (lds) + (f) * 8)

// --- Fenced sync primitives (validated r11/r12: rule #18 double-fence).
#define SCHED0   __builtin_amdgcn_sched_barrier(0)
#define ABAR     __builtin_amdgcn_s_barrier()
#define VMCNT(N) asm volatile("s_waitcnt vmcnt(" #N ")" ::: "memory")
#define LGKM0    asm volatile("s_waitcnt lgkmcnt(0)" ::: "memory")

// Per-wave 64x64 output, 16x16x32 bf16 MFMA, K=32 per step, 32-ushort rows.
#define PREAMBLE(WM, WN)                                \
    const int t = threadIdx.x;                          \
    const int wid = t >> 6, l = t & 63;                 \
    const int wm = (WM), wn = (WN);                     \
    const int l15 = l & 15, lhi = l >> 4;               \
    const int swz8 = (lhi ^ ((l15 >> 1) & 3)) * 8;      \
    f32x4 acc[4][4];                                    \
    _Pragma("unroll")                                   \
    for (int a_ = 0; a_ < 4; ++a_)                      \
        _Pragma("unroll")                               \
        for (int b_ = 0; b_ < 4; ++b_)                  \
            acc[a_][b_] = (f32x4){0.f, 0.f, 0.f, 0.f};

#define MFMA_STEP(As, Bs)                                                        \
    {                                                                            \
        bf16x8 af_[4], bf_[4];                                                   \
        _Pragma("unroll")                                                        \
        for (int f_ = 0; f_ < 4; ++f_) {                                         \
            af_[f_] = *(const bf16x8*)((As) + (wm*64 + f_*16 + l15)*32 + swz8);  \
            bf_[f_] = *(const bf16x8*)((Bs) + (wn*64 + f_*16 + l15)*32 + swz8);  \
        }                                                                        \
        _Pragma("unroll")                                                        \
        for (int m_ = 0; m_ < 4; ++m_)                                           \
            _Pragma("unroll")                                                    \
            for (int n_ = 0; n_ < 4; ++n_)                                       \
                acc[m_][n_] = __builtin_amdgcn_mfma_f32_16x16x32_bf16(           \
                    af_[m_], bf_[n_], acc[m_][n_], 0, 0, 0);                     \
    }

// Triple-buffered K-loop, ONE fenced barrier per step, prefetch distance 2
// (validated r12).  Requires A0..A2/B0..B2; each STG = 4 gll16/thread.
#define DBUFT(STG, NIT)                                                          \
    STG(0, A0, B0); STG(1, A1, B1);                                              \
    _Pragma("unroll")                                                            \
    for (int s = 0; s < (NIT); ++s) {                                            \
        if (s < (NIT) - 1) { VMCNT(4); } else { VMCNT(0); }                      \
        SCHED0; ABAR; SCHED0;                                                    \
        if (s + 2 < (NIT)) {                                                     \
            if (((s + 2) % 3) == 0)      { STG(s + 2, A0, B0); }                 \
            else if (((s + 2) % 3) == 1) { STG(s + 2, A1, B1); }                 \
            else                         { STG(s + 2, A2, B2); }                 \
        }                                                                        \
        if ((s % 3) == 0)      { MFMA_STEP(A0, B0); }                            \
        else if ((s % 3) == 1) { MFMA_STEP(A1, B1); }                            \
        else                   { MFMA_STEP(A2, B2); }                            \
    }

#define BUFS3 ushort* A0 = S;          ushort* B0 = S + 4096;                    \
              ushort* A1 = S + 8192;   ushort* B1 = S + 12288;                   \
              ushort* A2 = S + 16384;  ushort* B2 = S + 20480;

// ---------------------------------------------------------------------------
// Weights -> n-major bf16.
// ---------------------------------------------------------------------------
__global__ __launch_bounds__(256) void convert_w(
    const float* __restrict__ Wq, const float* __restrict__ Wk,
    const float* __restrict__ Wv, const float* __restrict__ Wo,
    ushort* __restrict__ WTqkv, ushort* __restrict__ WoT)
{
    const int id = blockIdx.x;      // 0..1023
    const int matn = id >> 8;
    const int n = id & 255;
    const int k = threadIdx.x;
    const float* W = (matn == 0) ? Wq : (matn == 1) ? Wk : (matn == 2) ? Wv : Wo;
    ushort v = f2bf(W[(size_t)k * E_ + n]);
    if (matn < 3) WTqkv[((size_t)matn * E_ + n) * E_ + k] = v;
    else          WoT[(size_t)n * E_ + k] = v;
}

// ---------------------------------------------------------------------------
// Fused QKV projection, conversion fused, A REG-STAGED to bf16 LDS (T14).
// Per step/thread: 4 float4 global loads (2 chunk-pairs, coalesced) -> 8
// cvt_pk -> 2 ds_write_b128 into a bf16 [128][32] A tile (64B rows, r12 key
// -> low-conflict standard MFMA_STEP).  B via gll16, triple-buffered.  ONE
// fenced barrier/step: VMCNT(6) [batch s landed, s+1 in flight] -> cvt+write
// A(s) -> LGKM0+barrier -> issue A-loads/B-gll(s+2) -> MFMA(s).
// A dbuf 2x8KB + B 3x8KB = 40KB.  12288 blocks x 256 thr (4 waves 2x2).
// ---------------------------------------------------------------------------
__global__ __launch_bounds__(256) void qkv_mfma(
    const float* __restrict__ x, const ushort* __restrict__ WT,
    const float* __restrict__ bq, const float* __restrict__ bk,
    const float* __restrict__ bv, const float* __restrict__ mask,
    ushort* __restrict__ qb, ushort* __restrict__ kb, ushort* __restrict__ vb)
{
    __shared__ __align__(16) ushort S[20480];   // 40KB; repack aliases front
    ushort* Ab0 = S;            // bf16 [128][32]
    ushort* Ab1 = S + 4096;
    ushort* Bb0 = S + 8192;
    ushort* Bb1 = S + 12288;
    ushort* Bb2 = S + 16384;
    const int id = ((blockIdx.x & 7) * 1536) + (blockIdx.x >> 3);
    const int nt = id % 6;
    const int rc0 = (id / 6) * 128;
    const int t = threadIdx.x;
    const int wid = t >> 6, l = t & 63;
    const int wm = wid >> 1, wn = wid & 1;
    const int l15 = l & 15, lhi = l >> 4;
    const int swz8 = (lhi ^ ((l15 >> 1) & 3)) * 8;
    f32x4 acc[4][4];
    #pragma unroll
    for (int a_ = 0; a_ < 4; ++a_)
        #pragma unroll
        for (int b_ = 0; b_ < 4; ++b_)
            acc[a_][b_] = (f32x4){0.f, 0.f, 0.f, 0.f};

    const float*  Ag = x + (size_t)rc0 * E_;
    const ushort* Bg = WT + (size_t)nt * 128 * E_;

    // A chunk geometry: thread t owns chunks f0=t (row0=t>>2) and f1=t+256
    // (row1=row0+64); stored slot = t&3, source chunk cc = (t&3)^((row0>>1)&3)
    // (key identical for row1 since +64 preserves (row>>1)&3).
    const int row0 = t >> 2;
    const int cc = (t & 3) ^ ((row0 >> 1) & 3);
    const float* Ap0 = Ag + (size_t)row0 * E_ + cc * 8;
    const float* Ap1 = Ag + (size_t)(row0 + 64) * E_ + cc * 8;
    const int ws0 = row0 * 32 + (t & 3) * 8;           // LDS write slots
    const int ws1 = (row0 + 64) * 32 + (t & 3) * 8;

    float4 rA0a, rA0b, rA0c, rA0d;   // reg set 0 (even steps)
    float4 rA1a, rA1b, rA1c, rA1d;   // reg set 1 (odd steps)

#define ALOAD0(i) { rA0a = *(const float4*)(Ap0 + (i)*32);                       \
                    rA0b = *(const float4*)(Ap0 + (i)*32 + 4);                   \
                    rA0c = *(const float4*)(Ap1 + (i)*32);                       \
                    rA0d = *(const float4*)(Ap1 + (i)*32 + 4); }
#define ALOAD1(i) { rA1a = *(const float4*)(Ap0 + (i)*32);                       \
                    rA1b = *(const float4*)(Ap0 + (i)*32 + 4);                   \
                    rA1c = *(const float4*)(Ap1 + (i)*32);                       \
                    rA1d = *(const float4*)(Ap1 + (i)*32 + 4); }
#define AWRITE0(buf) { uint4 w0_ = { cvtpk(rA0a.x,rA0a.y), cvtpk(rA0a.z,rA0a.w), \
                                     cvtpk(rA0b.x,rA0b.y), cvtpk(rA0b.z,rA0b.w)};\
                       uint4 w1_ = { cvtpk(rA0c.x,rA0c.y), cvtpk(rA0c.z,rA0c.w), \
                                     cvtpk(rA0d.x,rA0d.y), cvtpk(rA0d.z,rA0d.w)};\
                       *(uint4*)((buf) + ws0) = w0_;                             \
                       *(uint4*)((buf) + ws1) = w1_; }
#define AWRITE1(buf) { uint4 w0_ = { cvtpk(rA1a.x,rA1a.y), cvtpk(rA1a.z,rA1a.w), \
                                     cvtpk(rA1b.x,rA1b.y), cvtpk(rA1b.z,rA1b.w)};\
                       uint4 w1_ = { cvtpk(rA1c.x,rA1c.y), cvtpk(rA1c.z,rA1c.w), \
                                     cvtpk(rA1d.x,rA1d.y), cvtpk(rA1d.z,rA1d.w)};\
                       *(uint4*)((buf) + ws0) = w0_;                             \
                       *(uint4*)((buf) + ws1) = w1_; }
#define BGLL(i, buf) { const ushort* Bi_ = Bg + (i) * 32;                        \
                       SCH(Bi_, E_, buf, t); SCH(Bi_, E_, buf, t + 256); }

    // Prologue: batches 0 and 1 (each = 4 A-loads + 2 B-glls, in that order).
    ALOAD0(0); BGLL(0, Bb0);
    ALOAD1(1); BGLL(1, Bb1);

    #pragma unroll
    for (int s = 0; s < 8; ++s) {
        if (s < 7) { VMCNT(6); } else { VMCNT(0); }   // batch s landed
        SCHED0;
        if ((s & 1) == 0) { AWRITE0((s & 1) ? Ab1 : Ab0); }
        else              { AWRITE1((s & 1) ? Ab1 : Ab0); }
        LGKM0; SCHED0; ABAR; SCHED0;
        if (s + 2 < 8) {
            if ((s & 1) == 0) { ALOAD0(s + 2); }       // reuse set s&1
            else              { ALOAD1(s + 2); }
            if (((s + 2) % 3) == 0)      { BGLL(s + 2, Bb0); }
            else if (((s + 2) % 3) == 1) { BGLL(s + 2, Bb1); }
            else                         { BGLL(s + 2, Bb2); }
        }
        if ((s % 3) == 0)      { MFMA_STEP(((s & 1) ? Ab1 : Ab0), Bb0); }
        else if ((s % 3) == 1) { MFMA_STEP(((s & 1) ? Ab1 : Ab0), Bb1); }
        else                   { MFMA_STEP(((s & 1) ? Ab1 : Ab0), Bb2); }
    }
    __syncthreads();   // all staging reads done before repack alias

    const int proj = nt >> 1;
    const float* bias = (proj == 0) ? bq : (proj == 1) ? bk : bv;
    float bvv[4];
    #pragma unroll
    for (int fn = 0; fn < 4; ++fn)
        bvv[fn] = bias[(nt * 128 + wn * 64 + fn * 16 + l15) & 255];

    // repack: q/k as [c][e], v as [e][c]
    #pragma unroll
    for (int fm = 0; fm < 4; ++fm)
        #pragma unroll
        for (int fn = 0; fn < 4; ++fn)
            #pragma unroll
            for (int rg = 0; rg < 4; ++rg) {
                const int m = wm * 64 + fm * 16 + lhi * 4 + rg;
                const int n = wn * 64 + fn * 16 + l15;
                const ushort val = f2bf(acc[fm][fn][rg] + bvv[fn]);
                if (proj < 2) S[m * RP + n] = val;
                else          S[n * RP + m] = val;
            }
    __syncthreads();

    const int r = rc0 >> 9, c0 = rc0 & 511;
    if (proj < 2) {
        ushort* dst = (proj == 0) ? qb : kb;
        #pragma unroll
        for (int c = 0; c < 8; ++c) {
            const int idx = t + 256 * c;
            const int mrow = idx >> 4, ne = (idx & 15) * 8;
            uint4 w = *(const uint4*)(S + mrow * RP + ne);
            if (proj == 0) {   // q: * 1/128 * (1-mask)
                const float sk = 0.0078125f * (1.0f - mask[rc0 + mrow]);
                ushort* ws = (ushort*)&w;
                #pragma unroll
                for (int jj = 0; jj < 8; ++jj) ws[jj] = f2bf(bf2f(ws[jj]) * sk);
            }
            const int e = (nt & 1) * 128 + ne, h = e >> 5, d = e & 31;
            *(uint4*)(dst + ((((size_t)h * R_ + r) * C_) + c0 + mrow) * D_ + d) = w;
        }
    } else {
        #pragma unroll
        for (int c = 0; c < 8; ++c) {
            const int idx = t + 256 * c;
            const int nrow = idx >> 4, m0 = (idx & 15) * 8;
            uint4 w = *(const uint4*)(S + nrow * RP + m0);
            const int e = (nt & 1) * 128 + nrow, h = e >> 5, d = e & 31;
            *(uint4*)(vb + (((size_t)h * R_ + r) * D_ + d) * C_ + c0 + m0) = w;
        }
    }
#undef ALOAD0
#undef ALOAD1
#undef AWRITE0
#undef AWRITE1
#undef BGLL
}

// ---------------------------------------------------------------------------
// Attention logits.  128x128 tile, 256 threads, K split 8-way (1024 blocks).
// ---------------------------------------------------------------------------
__global__ __launch_bounds__(256) void logits_mfma(
    const ushort* __restrict__ qb, const ushort* __restrict__ kb,
    float* __restrict__ partial)
{
    __shared__ __align__(16) ushort S[24576];
    BUFS3;
    const int id = ((blockIdx.x & 7) * 128) + (blockIdx.x >> 3);
    const int sub = id & 15;
    const int j0 = (sub & 3) * 128;         // j fastest: 4 blocks share q panel
    const int i0 = (sub >> 2) * 128;
    const int hks = id >> 4;                // 0..63
    const int h = hks >> 3, ks = hks & 7;
    PREAMBLE(wid >> 1, wid & 1);

    const ushort* Ab = qb + (((size_t)h * R_ + ks * 64) * C_ + i0) * D_;
    const ushort* Bb = kb + (((size_t)h * R_ + ks * 64) * C_ + j0) * D_;

#define LSTG(i, Abuf, Bbuf) {                                   \
    const ushort* Ai = Ab + (size_t)(i) * (C_ * D_);            \
    const ushort* Bi = Bb + (size_t)(i) * (C_ * D_);            \
    SCH(Ai, D_, Abuf, t); SCH(Ai, D_, Abuf, t + 256);           \
    SCH(Bi, D_, Bbuf, t); SCH(Bi, D_, Bbuf, t + 256); }
    DBUFT(LSTG, 64);

    float* dst = partial + ((size_t)ks * H_ + h) * C_ * C_;
    #pragma unroll
    for (int fm = 0; fm < 4; ++fm)
        #pragma unroll
        for (int rg = 0; rg < 4; ++rg) {
            const int i = i0 + wm * 64 + fm * 16 + lhi * 4 + rg;
            #pragma unroll
            for (int fn = 0; fn < 4; ++fn) {
                const int j = j0 + wn * 64 + fn * 16 + l15;
                dst[(size_t)i * C_ + j] = acc[fm][fn][rg];
            }
        }
}

// ---------------------------------------------------------------------------
// Sum 8 K-split partials + i-axis mask + softmax over j.
// ---------------------------------------------------------------------------
__global__ __launch_bounds__(256) void softmax_kernel(
    const float* __restrict__ partial, const float* __restrict__ mask,
    float* __restrict__ probs, ushort* __restrict__ Pb)
{
    const int hi = blockIdx.x;
    const int i = hi & 511;
    const int t = threadIdx.x;
    const size_t base = (size_t)hi * C_;
    const size_t stride = (size_t)H_ * C_ * C_;
    float v0 = 0.f, v1 = 0.f;
    #pragma unroll
    for (int ksp = 0; ksp < 8; ++ksp) {
        v0 += partial[ksp * stride + base + t];
        v1 += partial[ksp * stride + base + t + 256];
    }
    const float mi = mask[i];
    const float keep = 1.0f - mi;
    v0 = v0 * keep + mi * (-10000.0f);
    v1 = v1 * keep + mi * (-10000.0f);

    float m = fmaxf(v0, v1);
    #pragma unroll
    for (int off = 32; off > 0; off >>= 1) m = fmaxf(m, __shfl_xor(m, off));
    __shared__ float red[4];
    if ((t & 63) == 0) red[t >> 6] = m;
    __syncthreads();
    m = fmaxf(fmaxf(red[0], red[1]), fmaxf(red[2], red[3]));

    const float e0 = expf(v0 - m), e1 = expf(v1 - m);
    float s = e0 + e1;
    #pragma unroll
    for (int off = 32; off > 0; off >>= 1) s += __shfl_xor(s, off);
    __syncthreads();
    if ((t & 63) == 0) red[t >> 6] = s;
    __syncthreads();
    s = red[0] + red[1] + red[2] + red[3];

    const float inv = 1.0f / s;
    const float p0 = e0 * inv, p1 = e1 * inv;
    probs[base + t] = p0;
    probs[base + t + 256] = p1;
    Pb[base + t] = f2bf(p0);
    Pb[base + t + 256] = f2bf(p1);
}

// ---------------------------------------------------------------------------
// Context.  128x128 tile, 256 threads, 4096 blocks (one head per XCD).
// ---------------------------------------------------------------------------
__global__ __launch_bounds__(256) void context_mfma(
    const ushort* __restrict__ Pb, const ushort* __restrict__ vb,
    ushort* __restrict__ ctxb)
{
    __shared__ __align__(16) ushort S[24576];
    BUFS3;
    const int id = ((blockIdx.x & 7) * 512) + (blockIdx.x >> 3);
    const int i0 = (id & 3) * 128;          // i fastest: 4 blocks share vb panel
    const int n0 = ((id >> 2) & 127) * 128;
    const int h = id >> 9;
    PREAMBLE(wid >> 1, wid & 1);

    const ushort* Ab = Pb + ((size_t)h * C_ + i0) * C_;
    const ushort* Bb = vb + ((size_t)h * R_ * D_ + n0) * C_;

#define CSTG(i, Abuf, Bbuf) {                                   \
    const ushort* Ai = Ab + (i) * 32;                           \
    const ushort* Bi = Bb + (i) * 32;                           \
    SCH(Ai, C_, Abuf, t); SCH(Ai, C_, Abuf, t + 256);           \
    SCH(Bi, C_, Bbuf, t); SCH(Bi, C_, Bbuf, t + 256); }
    DBUFT(CSTG, 16);
    __syncthreads();   // staging reads done before repack alias

    #pragma unroll
    for (int fm = 0; fm < 4; ++fm)
        #pragma unroll
        for (int fn = 0; fn < 4; ++fn)
            #pragma unroll
            for (int rg = 0; rg < 4; ++rg) {
                const int m = wm * 64 + fm * 16 + lhi * 4 + rg;
                const int n = wn * 64 + fn * 16 + l15;
                S[m * RP + n] = f2bf(acc[fm][fn][rg]);
            }
    __syncthreads();

    #pragma unroll
    for (int c = 0; c < 8; ++c) {
        const int idx = t + 256 * c;
        const int mrow = idx >> 4, nl = (idx & 15) * 8;
        uint4 w = *(const uint4*)(S + mrow * RP + nl);
        const int n = n0 + nl;
        const int rr = n >> 5, d = n & 31;
        const size_t rc = (size_t)rr * C_ + i0 + mrow;
        *(uint4*)(ctxb + rc * E_ + h * D_ + d) = w;
    }
}

// ---------------------------------------------------------------------------
// Output projection.  128x128 tile, 256 threads, 4096 blocks, fp32 out.
// ---------------------------------------------------------------------------
__global__ __launch_bounds__(256) void out_proj_mfma(
    const ushort* __restrict__ ctxb, const ushort* __restrict__ WoT,
    const float* __restrict__ bo, float* __restrict__ out)
{
    __shared__ __align__(16) ushort S[24576];
    BUFS3;
    float* Sf = (float*)S;                  // 128 x 68 fp32 repack (aliases)
    const int id = ((blockIdx.x & 7) * 512) + (blockIdx.x >> 3);
    const int n0 = (id & 1) * 128;
    const int rc0 = (id >> 1) * 128;
    PREAMBLE(wid >> 1, wid & 1);

    const ushort* Ab = ctxb + (size_t)rc0 * E_;
    const ushort* Bb = WoT + (size_t)n0 * E_;

#define OSTG(i, Abuf, Bbuf) {                                   \
    const ushort* Ai = Ab + (i) * 32;                           \
    const ushort* Bi = Bb + (i) * 32;                           \
    SCH(Ai, E_, Abuf, t); SCH(Ai, E_, Abuf, t + 256);           \
    SCH(Bi, E_, Bbuf, t); SCH(Bi, E_, Bbuf, t + 256); }
    DBUFT(OSTG, 8);
    __syncthreads();   // staging reads done before repack alias

    float bvv[4];
    #pragma unroll
    for (int fn = 0; fn < 4; ++fn)
        bvv[fn] = bo[n0 + wn * 64 + fn * 16 + l15];

    #pragma unroll
    for (int p = 0; p < 2; ++p) {
        #pragma unroll
        for (int fm = 0; fm < 4; ++fm)
            #pragma unroll
            for (int fh = 0; fh < 2; ++fh) {
                const int fn = 2 * p + fh;
                #pragma unroll
                for (int rg = 0; rg < 4; ++rg) {
                    const int m = wm * 64 + fm * 16 + lhi * 4 + rg;
                    const int s = wn * 32 + fh * 16 + l15;
                    Sf[m * 68 + s] = acc[fm][fn][rg] + bvv[fn];
                }
            }
        __syncthreads();
        #pragma unroll
        for (int c = 0; c < 8; ++c) {
            const int idx = t + 256 * c;
            const int row = idx >> 4, s0 = (idx & 15) * 4;
            float4 w = *(const float4*)(Sf + row * 68 + s0);
            const int ncol = n0 + (s0 >> 5) * 64 + (2 * p + ((s0 >> 4) & 1)) * 16 + (s0 & 15);
            *(float4*)(out + ((size_t)rc0 + row) * E_ + ncol) = w;
        }
        __syncthreads();
    }
}

// ---------------------------------------------------------------------------
extern "C" void kernel_launch(void* const* d_in, const int* in_sizes, int n_in,
                              void* d_out, int out_size, void* d_ws, size_t ws_size,
                              hipStream_t stream)
{
    const float* x    = (const float*)d_in[0];
    const float* mask = (const float*)d_in[1];
    const float* Wq   = (const float*)d_in[2];
    const float* bq   = (const float*)d_in[3];
    const float* Wk   = (const float*)d_in[4];
    const float* bk   = (const float*)d_in[5];
    const float* Wv   = (const float*)d_in[6];
    const float* bv   = (const float*)d_in[7];
    const float* Wo   = (const float*)d_in[8];
    const float* bo   = (const float*)d_in[9];

    float* out   = (float*)d_out;                       // [R,C,E] fp32
    float* probs = out + (size_t)RC_ * E_;              // [H,C,C] fp32

    char* ws = (char*)d_ws;
    ushort* qb      = (ushort*)(ws);                    // 128 MB  [h][r][c][d]
    ushort* kb      = (ushort*)(ws + 134217728ull);     // 128 MB  [h][r][c][d]
    ushort* vb      = (ushort*)(ws + 268435456ull);     // 128 MB  [h][r][d][c]
    ushort* ctxb    = (ushort*)(ws + 402653184ull);     // 128 MB  [rc][e]
    float*  partial = (float*)(ws + 536870912ull);      // 64 MB   [8][h][i][j]
    ushort* Pb      = (ushort*)(ws + 603979776ull);     // 4 MB    [h][i][j]
    ushort* WTqkv   = (ushort*)(ws + 608174080ull);     // 384 KB
    ushort* WoT     = (ushort*)(ws + 608567296ull);     // 128 KB

    convert_w<<<1024, 256, 0, stream>>>(Wq, Wk, Wv, Wo, WTqkv, WoT);
    qkv_mfma<<<12288, 256, 0, stream>>>(x, WTqkv, bq, bk, bv, mask, qb, kb, vb);
    logits_mfma<<<1024, 256, 0, stream>>>(qb, kb, partial);
    softmax_kernel<<<4096, 256, 0, stream>>>(partial, mask, probs, Pb);
    context_mfma<<<4096, 256, 0, stream>>>(Pb, vb, ctxb);
    out_proj_mfma<<<4096, 256, 0, stream>>>(ctxb, WoT, bo, out);
}

// Round 16
// 575.896 us; speedup vs baseline: 1.0690x; 1.0479x over previous
//
#include <hip/hip_runtime.h>
#include <math.h>

#define R_ 512
#define C_ 512
#define E_ 256
#define H_ 8
#define D_ 32
#define RC_ (R_*C_)   // 262144
#define RP 136        // repack pitch (ushorts)

typedef __attribute__((ext_vector_type(8))) short bf16x8;
typedef __attribute__((ext_vector_type(4))) float f32x4;

__device__ __forceinline__ ushort f2bf(float f) {
    union { float f; unsigned u; } v; v.f = f;
    unsigned r = v.u + 0x7FFFu + ((v.u >> 16) & 1u);   // RNE
    return (ushort)(r >> 16);
}
__device__ __forceinline__ float bf2f(ushort u) {
    union { unsigned u; float f; } v; v.u = ((unsigned)u) << 16;
    return v.f;
}
// packed f32x2 -> bf16x2 (RNE on gfx950)
__device__ __forceinline__ unsigned cvtpk(float lo, float hi) {
    unsigned r;
    asm("v_cvt_pk_bf16_f32 %0, %1, %2" : "=v"(r) : "v"(lo), "v"(hi));
    return r;
}

// 16B global->LDS direct copy (lane-linear dest), fallback = reg staging.
__device__ __forceinline__ void gll16(const ushort* g, ushort* l) {
#if __has_builtin(__builtin_amdgcn_global_load_lds)
    __builtin_amdgcn_global_load_lds(
        (const __attribute__((address_space(1))) unsigned*)(unsigned long long)g,
        (__attribute__((address_space(3))) unsigned*)(unsigned)(unsigned long long)l,
        16, 0, 0);
#else
    *(uint4*)l = *(const uint4*)g;
#endif
}

// Stage one 16B chunk f of a [rows][32-ushort] bf16 tile.  Source slot
// XOR-swizzled with (row>>1)&3 (r12-proven key).  LDS dest lane-linear.
#define SCH(gbase, stride, lds, f)                                               \
    gll16((gbase) + (size_t)((f) >> 2) * (stride)                                \
              + (((((f) & 3) ^ ((((f) >> 2) >> 1) & 3))) << 3),                  \
          (lds) + (f) * 8)

// --- Fenced sync primitives (validated r11/r12: rule #18 double-fence).
#define SCHED0   __builtin_amdgcn_sched_barrier(0)
#define ABAR     __builtin_amdgcn_s_barrier()
#define VMCNT(N) asm volatile("s_waitcnt vmcnt(" #N ")" ::: "memory")
#define LGKM0    asm volatile("s_waitcnt lgkmcnt(0)" ::: "memory")

// Per-wave 64x64 output, 16x16x32 bf16 MFMA, K=32 per step, 32-ushort rows.
#define PREAMBLE(WM, WN)                                \
    const int t = threadIdx.x;                          \
    const int wid = t >> 6, l = t & 63;                 \
    const int wm = (WM), wn = (WN);                     \
    const int l15 = l & 15, lhi = l >> 4;               \
    const int swz8 = (lhi ^ ((l15 >> 1) & 3)) * 8;      \
    f32x4 acc[4][4];                                    \
    _Pragma("unroll")                                   \
    for (int a_ = 0; a_ < 4; ++a_)                      \
        _Pragma("unroll")                               \
        for (int b_ = 0; b_ < 4; ++b_)                  \
            acc[a_][b_] = (f32x4){0.f, 0.f, 0.f, 0.f};

#define MFMA_STEP(As, Bs)                                                        \
    {                                                                            \
        bf16x8 af_[4], bf_[4];                                                   \
        _Pragma("unroll")                                                        \
        for (int f_ = 0; f_ < 4; ++f_) {                                         \
            af_[f_] = *(const bf16x8*)((As) + (wm*64 + f_*16 + l15)*32 + swz8);  \
            bf_[f_] = *(const bf16x8*)((Bs) + (wn*64 + f_*16 + l15)*32 + swz8);  \
        }                                                                        \
        _Pragma("unroll")                                                        \
        for (int m_ = 0; m_ < 4; ++m_)                                           \
            _Pragma("unroll")                                                    \
            for (int n_ = 0; n_ < 4; ++n_)                                       \
                acc[m_][n_] = __builtin_amdgcn_mfma_f32_16x16x32_bf16(           \
                    af_[m_], bf_[n_], acc[m_][n_], 0, 0, 0);                     \
    }

// Triple-buffered K-loop, ONE fenced barrier per step, prefetch distance 2
// (validated r12).  Requires A0..A2/B0..B2; each STG = 4 gll16/thread.
#define DBUFT(STG, NIT)                                                          \
    STG(0, A0, B0); STG(1, A1, B1);                                              \
    _Pragma("unroll")                                                            \
    for (int s = 0; s < (NIT); ++s) {                                            \
        if (s < (NIT) - 1) { VMCNT(4); } else { VMCNT(0); }                      \
        SCHED0; ABAR; SCHED0;                                                    \
        if (s + 2 < (NIT)) {                                                     \
            if (((s + 2) % 3) == 0)      { STG(s + 2, A0, B0); }                 \
            else if (((s + 2) % 3) == 1) { STG(s + 2, A1, B1); }                 \
            else                         { STG(s + 2, A2, B2); }                 \
        }                                                                        \
        if ((s % 3) == 0)      { MFMA_STEP(A0, B0); }                            \
        else if ((s % 3) == 1) { MFMA_STEP(A1, B1); }                            \
        else                   { MFMA_STEP(A2, B2); }                            \
    }

#define BUFS3 ushort* A0 = S;          ushort* B0 = S + 4096;                    \
              ushort* A1 = S + 8192;   ushort* B1 = S + 12288;                   \
              ushort* A2 = S + 16384;  ushort* B2 = S + 20480;

// ---------------------------------------------------------------------------
// Weights -> n-major bf16.
// ---------------------------------------------------------------------------
__global__ __launch_bounds__(256) void convert_w(
    const float* __restrict__ Wq, const float* __restrict__ Wk,
    const float* __restrict__ Wv, const float* __restrict__ Wo,
    ushort* __restrict__ WTqkv, ushort* __restrict__ WoT)
{
    const int id = blockIdx.x;      // 0..1023
    const int matn = id >> 8;
    const int n = id & 255;
    const int k = threadIdx.x;
    const float* W = (matn == 0) ? Wq : (matn == 1) ? Wk : (matn == 2) ? Wv : Wo;
    ushort v = f2bf(W[(size_t)k * E_ + n]);
    if (matn < 3) WTqkv[((size_t)matn * E_ + n) * E_ + k] = v;
    else          WoT[(size_t)n * E_ + k] = v;
}

// ---------------------------------------------------------------------------
// Fused QKV projection: 512 threads (8 waves 2x4), 128x128 tile.  Same fenced
// reg-staged schedule as r15 but per-wave work halved (acc[4][2], 8 MFMA +
// 6 ds_read/step) and per-thread staging halved (2 A float4 + 1 B gll,
// VMCNT(3)).  LDS unchanged 40KB -> 4 blocks/CU x 8 waves = 32 waves/CU.
// ---------------------------------------------------------------------------
__global__ __launch_bounds__(512) void qkv_mfma(
    const float* __restrict__ x, const ushort* __restrict__ WT,
    const float* __restrict__ bq, const float* __restrict__ bk,
    const float* __restrict__ bv, const float* __restrict__ mask,
    ushort* __restrict__ qb, ushort* __restrict__ kb, ushort* __restrict__ vb)
{
    __shared__ __align__(16) ushort S[20480];   // 40KB; repack aliases front
    ushort* Ab0 = S;            // bf16 [128][32]
    ushort* Ab1 = S + 4096;
    ushort* Bb0 = S + 8192;
    ushort* Bb1 = S + 12288;
    ushort* Bb2 = S + 16384;
    const int id = ((blockIdx.x & 7) * 1536) + (blockIdx.x >> 3);
    const int nt = id % 6;
    const int rc0 = (id / 6) * 128;
    const int t = threadIdx.x;
    const int wid = t >> 6, l = t & 63;
    const int wm = wid >> 2, wn = wid & 3;   // 2 x 4 waves: 64m x 32n each
    const int l15 = l & 15, lhi = l >> 4;
    const int swz8 = (lhi ^ ((l15 >> 1) & 3)) * 8;
    f32x4 acc[4][2];
    #pragma unroll
    for (int a_ = 0; a_ < 4; ++a_)
        #pragma unroll
        for (int b_ = 0; b_ < 2; ++b_)
            acc[a_][b_] = (f32x4){0.f, 0.f, 0.f, 0.f};

    const float*  Ag = x + (size_t)rc0 * E_;
    const ushort* Bg = WT + (size_t)nt * 128 * E_;

    // A: thread t owns one bf16 16B chunk: row = t>>2 (0..127), slot = t&3;
    // source fp32 chunk cc = slot ^ ((row>>1)&3) (r12 key).
    const int rowA = t >> 2;
    const int ccA = (t & 3) ^ ((rowA >> 1) & 3);
    const float* Ap = Ag + (size_t)rowA * E_ + ccA * 8;
    const int wsA = rowA * 32 + (t & 3) * 8;

    float4 rA0a, rA0b;   // reg set 0 (even steps)
    float4 rA1a, rA1b;   // reg set 1 (odd steps)

#define ALOAD0(i) { rA0a = *(const float4*)(Ap + (i)*32);                        \
                    rA0b = *(const float4*)(Ap + (i)*32 + 4); }
#define ALOAD1(i) { rA1a = *(const float4*)(Ap + (i)*32);                        \
                    rA1b = *(const float4*)(Ap + (i)*32 + 4); }
#define AWRITE0(buf) { uint4 w_ = { cvtpk(rA0a.x,rA0a.y), cvtpk(rA0a.z,rA0a.w),  \
                                    cvtpk(rA0b.x,rA0b.y), cvtpk(rA0b.z,rA0b.w)}; \
                       *(uint4*)((buf) + wsA) = w_; }
#define AWRITE1(buf) { uint4 w_ = { cvtpk(rA1a.x,rA1a.y), cvtpk(rA1a.z,rA1a.w),  \
                                    cvtpk(rA1b.x,rA1b.y), cvtpk(rA1b.z,rA1b.w)}; \
                       *(uint4*)((buf) + wsA) = w_; }
#define BGLL(i, buf) { const ushort* Bi_ = Bg + (i) * 32;                        \
                       SCH(Bi_, E_, buf, t); }
#define QMFMA(As, Bs) {                                                          \
    bf16x8 af_[4], bf_[2];                                                       \
    _Pragma("unroll")                                                            \
    for (int f_ = 0; f_ < 4; ++f_)                                               \
        af_[f_] = *(const bf16x8*)((As) + (wm*64 + f_*16 + l15)*32 + swz8);      \
    _Pragma("unroll")                                                            \
    for (int g_ = 0; g_ < 2; ++g_)                                               \
        bf_[g_] = *(const bf16x8*)((Bs) + (wn*32 + g_*16 + l15)*32 + swz8);      \
    _Pragma("unroll")                                                            \
    for (int m_ = 0; m_ < 4; ++m_)                                               \
        _Pragma("unroll")                                                        \
        for (int n_ = 0; n_ < 2; ++n_)                                           \
            acc[m_][n_] = __builtin_amdgcn_mfma_f32_16x16x32_bf16(               \
                af_[m_], bf_[n_], acc[m_][n_], 0, 0, 0); }

    // Prologue: batches 0 and 1 (each = 2 A float4 loads + 1 B gll).
    ALOAD0(0); BGLL(0, Bb0);
    ALOAD1(1); BGLL(1, Bb1);

    #pragma unroll
    for (int s = 0; s < 8; ++s) {
        if (s < 7) { VMCNT(3); } else { VMCNT(0); }   // batch s landed
        SCHED0;
        if ((s & 1) == 0) { AWRITE0((s & 1) ? Ab1 : Ab0); }
        else              { AWRITE1((s & 1) ? Ab1 : Ab0); }
        LGKM0; SCHED0; ABAR; SCHED0;
        if (s + 2 < 8) {
            if ((s & 1) == 0) { ALOAD0(s + 2); }       // reuse set s&1
            else              { ALOAD1(s + 2); }
            if (((s + 2) % 3) == 0)      { BGLL(s + 2, Bb0); }
            else if (((s + 2) % 3) == 1) { BGLL(s + 2, Bb1); }
            else                         { BGLL(s + 2, Bb2); }
        }
        if ((s % 3) == 0)      { QMFMA(((s & 1) ? Ab1 : Ab0), Bb0); }
        else if ((s % 3) == 1) { QMFMA(((s & 1) ? Ab1 : Ab0), Bb1); }
        else                   { QMFMA(((s & 1) ? Ab1 : Ab0), Bb2); }
    }
    __syncthreads();   // all staging reads done before repack alias

    const int proj = nt >> 1;
    const float* bias = (proj == 0) ? bq : (proj == 1) ? bk : bv;
    float bvv[2];
    #pragma unroll
    for (int g = 0; g < 2; ++g)
        bvv[g] = bias[(nt * 128 + wn * 32 + g * 16 + l15) & 255];

    // repack: q/k as [c][e], v as [e][c]
    #pragma unroll
    for (int fm = 0; fm < 4; ++fm)
        #pragma unroll
        for (int g = 0; g < 2; ++g)
            #pragma unroll
            for (int rg = 0; rg < 4; ++rg) {
                const int m = wm * 64 + fm * 16 + lhi * 4 + rg;
                const int n = wn * 32 + g * 16 + l15;
                const ushort val = f2bf(acc[fm][g][rg] + bvv[g]);
                if (proj < 2) S[m * RP + n] = val;
                else          S[n * RP + m] = val;
            }
    __syncthreads();

    const int r = rc0 >> 9, c0 = rc0 & 511;
    if (proj < 2) {
        ushort* dst = (proj == 0) ? qb : kb;
        #pragma unroll
        for (int c = 0; c < 4; ++c) {
            const int idx = t + 512 * c;
            const int mrow = idx >> 4, ne = (idx & 15) * 8;
            uint4 w = *(const uint4*)(S + mrow * RP + ne);
            if (proj == 0) {   // q: * 1/128 * (1-mask)
                const float sk = 0.0078125f * (1.0f - mask[rc0 + mrow]);
                ushort* ws = (ushort*)&w;
                #pragma unroll
                for (int jj = 0; jj < 8; ++jj) ws[jj] = f2bf(bf2f(ws[jj]) * sk);
            }
            const int e = (nt & 1) * 128 + ne, h = e >> 5, d = e & 31;
            *(uint4*)(dst + ((((size_t)h * R_ + r) * C_) + c0 + mrow) * D_ + d) = w;
        }
    } else {
        #pragma unroll
        for (int c = 0; c < 4; ++c) {
            const int idx = t + 512 * c;
            const int nrow = idx >> 4, m0 = (idx & 15) * 8;
            uint4 w = *(const uint4*)(S + nrow * RP + m0);
            const int e = (nt & 1) * 128 + nrow, h = e >> 5, d = e & 31;
            *(uint4*)(vb + (((size_t)h * R_ + r) * D_ + d) * C_ + c0 + m0) = w;
        }
    }
#undef ALOAD0
#undef ALOAD1
#undef AWRITE0
#undef AWRITE1
#undef BGLL
#undef QMFMA
}

// ---------------------------------------------------------------------------
// Attention logits.  128x128 tile, 256 threads, K split 8-way (1024 blocks).
// ---------------------------------------------------------------------------
__global__ __launch_bounds__(256) void logits_mfma(
    const ushort* __restrict__ qb, const ushort* __restrict__ kb,
    float* __restrict__ partial)
{
    __shared__ __align__(16) ushort S[24576];
    BUFS3;
    const int id = ((blockIdx.x & 7) * 128) + (blockIdx.x >> 3);
    const int sub = id & 15;
    const int j0 = (sub & 3) * 128;         // j fastest: 4 blocks share q panel
    const int i0 = (sub >> 2) * 128;
    const int hks = id >> 4;                // 0..63
    const int h = hks >> 3, ks = hks & 7;
    PREAMBLE(wid >> 1, wid & 1);

    const ushort* Ab = qb + (((size_t)h * R_ + ks * 64) * C_ + i0) * D_;
    const ushort* Bb = kb + (((size_t)h * R_ + ks * 64) * C_ + j0) * D_;

#define LSTG(i, Abuf, Bbuf) {                                   \
    const ushort* Ai = Ab + (size_t)(i) * (C_ * D_);            \
    const ushort* Bi = Bb + (size_t)(i) * (C_ * D_);            \
    SCH(Ai, D_, Abuf, t); SCH(Ai, D_, Abuf, t + 256);           \
    SCH(Bi, D_, Bbuf, t); SCH(Bi, D_, Bbuf, t + 256); }
    DBUFT(LSTG, 64);

    float* dst = partial + ((size_t)ks * H_ + h) * C_ * C_;
    #pragma unroll
    for (int fm = 0; fm < 4; ++fm)
        #pragma unroll
        for (int rg = 0; rg < 4; ++rg) {
            const int i = i0 + wm * 64 + fm * 16 + lhi * 4 + rg;
            #pragma unroll
            for (int fn = 0; fn < 4; ++fn) {
                const int j = j0 + wn * 64 + fn * 16 + l15;
                dst[(size_t)i * C_ + j] = acc[fm][fn][rg];
            }
        }
}

// ---------------------------------------------------------------------------
// Sum 8 K-split partials + i-axis mask + softmax over j.
// ---------------------------------------------------------------------------
__global__ __launch_bounds__(256) void softmax_kernel(
    const float* __restrict__ partial, const float* __restrict__ mask,
    float* __restrict__ probs, ushort* __restrict__ Pb)
{
    const int hi = blockIdx.x;
    const int i = hi & 511;
    const int t = threadIdx.x;
    const size_t base = (size_t)hi * C_;
    const size_t stride = (size_t)H_ * C_ * C_;
    float v0 = 0.f, v1 = 0.f;
    #pragma unroll
    for (int ksp = 0; ksp < 8; ++ksp) {
        v0 += partial[ksp * stride + base + t];
        v1 += partial[ksp * stride + base + t + 256];
    }
    const float mi = mask[i];
    const float keep = 1.0f - mi;
    v0 = v0 * keep + mi * (-10000.0f);
    v1 = v1 * keep + mi * (-10000.0f);

    float m = fmaxf(v0, v1);
    #pragma unroll
    for (int off = 32; off > 0; off >>= 1) m = fmaxf(m, __shfl_xor(m, off));
    __shared__ float red[4];
    if ((t & 63) == 0) red[t >> 6] = m;
    __syncthreads();
    m = fmaxf(fmaxf(red[0], red[1]), fmaxf(red[2], red[3]));

    const float e0 = expf(v0 - m), e1 = expf(v1 - m);
    float s = e0 + e1;
    #pragma unroll
    for (int off = 32; off > 0; off >>= 1) s += __shfl_xor(s, off);
    __syncthreads();
    if ((t & 63) == 0) red[t >> 6] = s;
    __syncthreads();
    s = red[0] + red[1] + red[2] + red[3];

    const float inv = 1.0f / s;
    const float p0 = e0 * inv, p1 = e1 * inv;
    probs[base + t] = p0;
    probs[base + t + 256] = p1;
    Pb[base + t] = f2bf(p0);
    Pb[base + t + 256] = f2bf(p1);
}

// ---------------------------------------------------------------------------
// Context.  128x128 tile, 256 threads, 4096 blocks (one head per XCD).
// ---------------------------------------------------------------------------
__global__ __launch_bounds__(256) void context_mfma(
    const ushort* __restrict__ Pb, const ushort* __restrict__ vb,
    ushort* __restrict__ ctxb)
{
    __shared__ __align__(16) ushort S[24576];
    BUFS3;
    const int id = ((blockIdx.x & 7) * 512) + (blockIdx.x >> 3);
    const int i0 = (id & 3) * 128;          // i fastest: 4 blocks share vb panel
    const int n0 = ((id >> 2) & 127) * 128;
    const int h = id >> 9;
    PREAMBLE(wid >> 1, wid & 1);

    const ushort* Ab = Pb + ((size_t)h * C_ + i0) * C_;
    const ushort* Bb = vb + ((size_t)h * R_ * D_ + n0) * C_;

#define CSTG(i, Abuf, Bbuf) {                                   \
    const ushort* Ai = Ab + (i) * 32;                           \
    const ushort* Bi = Bb + (i) * 32;                           \
    SCH(Ai, C_, Abuf, t); SCH(Ai, C_, Abuf, t + 256);           \
    SCH(Bi, C_, Bbuf, t); SCH(Bi, C_, Bbuf, t + 256); }
    DBUFT(CSTG, 16);
    __syncthreads();   // staging reads done before repack alias

    #pragma unroll
    for (int fm = 0; fm < 4; ++fm)
        #pragma unroll
        for (int fn = 0; fn < 4; ++fn)
            #pragma unroll
            for (int rg = 0; rg < 4; ++rg) {
                const int m = wm * 64 + fm * 16 + lhi * 4 + rg;
                const int n = wn * 64 + fn * 16 + l15;
                S[m * RP + n] = f2bf(acc[fm][fn][rg]);
            }
    __syncthreads();

    #pragma unroll
    for (int c = 0; c < 8; ++c) {
        const int idx = t + 256 * c;
        const int mrow = idx >> 4, nl = (idx & 15) * 8;
        uint4 w = *(const uint4*)(S + mrow * RP + nl);
        const int n = n0 + nl;
        const int rr = n >> 5, d = n & 31;
        const size_t rc = (size_t)rr * C_ + i0 + mrow;
        *(uint4*)(ctxb + rc * E_ + h * D_ + d) = w;
    }
}

// ---------------------------------------------------------------------------
// Output projection.  128x128 tile, 256 threads, 4096 blocks, fp32 out.
// ---------------------------------------------------------------------------
__global__ __launch_bounds__(256) void out_proj_mfma(
    const ushort* __restrict__ ctxb, const ushort* __restrict__ WoT,
    const float* __restrict__ bo, float* __restrict__ out)
{
    __shared__ __align__(16) ushort S[24576];
    BUFS3;
    float* Sf = (float*)S;                  // 128 x 68 fp32 repack (aliases)
    const int id = ((blockIdx.x & 7) * 512) + (blockIdx.x >> 3);
    const int n0 = (id & 1) * 128;
    const int rc0 = (id >> 1) * 128;
    PREAMBLE(wid >> 1, wid & 1);

    const ushort* Ab = ctxb + (size_t)rc0 * E_;
    const ushort* Bb = WoT + (size_t)n0 * E_;

#define OSTG(i, Abuf, Bbuf) {                                   \
    const ushort* Ai = Ab + (i) * 32;                           \
    const ushort* Bi = Bb + (i) * 32;                           \
    SCH(Ai, E_, Abuf, t); SCH(Ai, E_, Abuf, t + 256);           \
    SCH(Bi, E_, Bbuf, t); SCH(Bi, E_, Bbuf, t + 256); }
    DBUFT(OSTG, 8);
    __syncthreads();   // staging reads done before repack alias

    float bvv[4];
    #pragma unroll
    for (int fn = 0; fn < 4; ++fn)
        bvv[fn] = bo[n0 + wn * 64 + fn * 16 + l15];

    #pragma unroll
    for (int p = 0; p < 2; ++p) {
        #pragma unroll
        for (int fm = 0; fm < 4; ++fm)
            #pragma unroll
            for (int fh = 0; fh < 2; ++fh) {
                const int fn = 2 * p + fh;
                #pragma unroll
                for (int rg = 0; rg < 4; ++rg) {
                    const int m = wm * 64 + fm * 16 + lhi * 4 + rg;
                    const int s = wn * 32 + fh * 16 + l15;
                    Sf[m * 68 + s] = acc[fm][fn][rg] + bvv[fn];
                }
            }
        __syncthreads();
        #pragma unroll
        for (int c = 0; c < 8; ++c) {
            const int idx = t + 256 * c;
            const int row = idx >> 4, s0 = (idx & 15) * 4;
            float4 w = *(const float4*)(Sf + row * 68 + s0);
            const int ncol = n0 + (s0 >> 5) * 64 + (2 * p + ((s0 >> 4) & 1)) * 16 + (s0 & 15);
            *(float4*)(out + ((size_t)rc0 + row) * E_ + ncol) = w;
        }
        __syncthreads();
    }
}

// ---------------------------------------------------------------------------
extern "C" void kernel_launch(void* const* d_in, const int* in_sizes, int n_in,
                              void* d_out, int out_size, void* d_ws, size_t ws_size,
                              hipStream_t stream)
{
    const float* x    = (const float*)d_in[0];
    const float* mask = (const float*)d_in[1];
    const float* Wq   = (const float*)d_in[2];
    const float* bq   = (const float*)d_in[3];
    const float* Wk   = (const float*)d_in[4];
    const float* bk   = (const float*)d_in[5];
    const float* Wv   = (const float*)d_in[6];
    const float* bv   = (const float*)d_in[7];
    const float* Wo   = (const float*)d_in[8];
    const float* bo   = (const float*)d_in[9];

    float* out   = (float*)d_out;                       // [R,C,E] fp32
    float* probs = out + (size_t)RC_ * E_;              // [H,C,C] fp32

    char* ws = (char*)d_ws;
    ushort* qb      = (ushort*)(ws);                    // 128 MB  [h][r][c][d]
    ushort* kb      = (ushort*)(ws + 134217728ull);     // 128 MB  [h][r][c][d]
    ushort* vb      = (ushort*)(ws + 268435456ull);     // 128 MB  [h][r][d][c]
    ushort* ctxb    = (ushort*)(ws + 402653184ull);     // 128 MB  [rc][e]
    float*  partial = (float*)(ws + 536870912ull);      // 64 MB   [8][h][i][j]
    ushort* Pb      = (ushort*)(ws + 603979776ull);     // 4 MB    [h][i][j]
    ushort* WTqkv   = (ushort*)(ws + 608174080ull);     // 384 KB
    ushort* WoT     = (ushort*)(ws + 608567296ull);     // 128 KB

    convert_w<<<1024, 256, 0, stream>>>(Wq, Wk, Wv, Wo, WTqkv, WoT);
    qkv_mfma<<<12288, 512, 0, stream>>>(x, WTqkv, bq, bk, bv, mask, qb, kb, vb);
    logits_mfma<<<1024, 256, 0, stream>>>(qb, kb, partial);
    softmax_kernel<<<4096, 256, 0, stream>>>(partial, mask, probs, Pb);
    context_mfma<<<4096, 256, 0, stream>>>(Pb, vb, ctxb);
    out_proj_mfma<<<4096, 256, 0, stream>>>(ctxb, WoT, bo, out);
}